// Round 10
// baseline (839.267 us; speedup 1.0000x reference)
//
#include <hip/hip_runtime.h>
#include <hip/hip_bf16.h>
#include <math.h>

#define BB 2
#define TT 1024
#define BT (BB*TT)          // 2048 rows
#define DM 1024
#define DI 2048
#define DS 128
#define NHS 32              // ssm heads
#define PDIM 64             // ssm headdim
#define NHA 16              // attn heads
#define HD 64
#define FFN_ 4096
#define NZX 4384            // 2*DI + 2*DS + NHS
#define NXBC 2304           // DI + 2*DS
#define NXBCD 2336          // xBC (2304) + dt (32) raw gemm-out width
#define CL 128              // scan chunk length
#define NC 8                // chunks

typedef __hip_bfloat16 bf16;
typedef short bf16x8 __attribute__((ext_vector_type(8)));
typedef float f32x4 __attribute__((ext_vector_type(4)));

__device__ __forceinline__ float b2f(bf16 v){ return __bfloat162float(v); }
__device__ __forceinline__ bf16 f2b(float v){ return __float2bfloat16(v); }

// ---------------- RMSNorm: write fp32 X copy + bf16 normalized H -------------
__global__ void k_rms_in(const float* __restrict__ xin, float* __restrict__ X,
                         bf16* __restrict__ H) {
  int row = blockIdx.x;
  int tid = threadIdx.x;          // 256 threads, 4 elems each (DM=1024)
  const float* xr = xin + (size_t)row * DM;
  float v[4]; float ss = 0.f;
  #pragma unroll
  for (int i = 0; i < 4; ++i) { v[i] = xr[tid*4+i]; ss += v[i]*v[i]; }
  __shared__ float red[256];
  red[tid] = ss; __syncthreads();
  for (int s = 128; s > 0; s >>= 1) { if (tid < s) red[tid] += red[tid+s]; __syncthreads(); }
  float scale = rsqrtf(red[0]/(float)DM + 1e-6f);
  float* Xr = X + (size_t)row*DM; bf16* Hr = H + (size_t)row*DM;
  #pragma unroll
  for (int i = 0; i < 4; ++i) { Xr[tid*4+i] = v[i]; Hr[tid*4+i] = f2b(v[i]*scale); }
}

__global__ void k_rms_f32(const float* __restrict__ X, bf16* __restrict__ H) {
  int row = blockIdx.x;
  int tid = threadIdx.x;
  const float* xr = X + (size_t)row * DM;
  float v[4]; float ss = 0.f;
  #pragma unroll
  for (int i = 0; i < 4; ++i) { v[i] = xr[tid*4+i]; ss += v[i]*v[i]; }
  __shared__ float red[256];
  red[tid] = ss; __syncthreads();
  for (int s = 128; s > 0; s >>= 1) { if (tid < s) red[tid] += red[tid+s]; __syncthreads(); }
  float scale = rsqrtf(red[0]/(float)DM + 1e-6f);
  bf16* Hr = H + (size_t)row*DM;
  #pragma unroll
  for (int i = 0; i < 4; ++i) Hr[tid*4+i] = f2b(v[i]*scale);
}

// ---------------- weight cast + transpose: Wt[n][k] = bf16(W[k][n]) ----------
__global__ void k_tcast(const float* __restrict__ W, bf16* __restrict__ Wt,
                        int K, int N) {
  __shared__ float t[32][33];
  int tx = threadIdx.x, ty = threadIdx.y;
  int n0 = blockIdx.x*32, k0 = blockIdx.y*32;
  #pragma unroll
  for (int i = 0; i < 4; ++i) {
    int k = k0 + ty + i*8, n = n0 + tx;
    t[ty + i*8][tx] = (n < N) ? W[(size_t)k*N + n] : 0.f;
  }
  __syncthreads();
  #pragma unroll
  for (int i = 0; i < 4; ++i) {
    int n = n0 + ty + i*8, k = k0 + tx;
    Wt[(size_t)n*K + k] = f2b(t[tx][ty + i*8]);
  }
}

// ---------------- MFMA GEMM 128x128: C[M,N] = epi(A @ Bt^T) ------------------
// Register-pipelined BK=64; LDS-staged contiguous epilogue stores.
template<int EPI, bool ADD, bool OUTBF>
__global__ __launch_bounds__(256)
void mfma_gemm(const bf16* __restrict__ A, const bf16* __restrict__ Bt,
               float* __restrict__ C, bf16* __restrict__ Cbf,
               int M, int N, int K) {
  __shared__ __align__(16) char smem[36864];
  bf16* As = (bf16*)smem;
  bf16* Bs = (bf16*)(smem + 18432);
  int tid = threadIdx.x;
  int wave = tid >> 6, lane = tid & 63;
  int m_l = lane & 15, quad = lane >> 4;
  int wr = (wave & 1) * 64, wc = (wave >> 1) * 64;
  int row0 = blockIdx.y * 128, col0 = blockIdx.x * 128;
  f32x4 acc[4][4];
  #pragma unroll
  for (int i = 0; i < 4; ++i)
    #pragma unroll
    for (int j = 0; j < 4; ++j) acc[i][j] = (f32x4){0.f,0.f,0.f,0.f};
  int r_a = tid >> 2;            // 0..63
  int kc  = (tid & 3) * 16;      // 0,16,32,48
  uint4 av[4], bv[4];
  const bf16* Arow0 = &A [(size_t)(row0      + r_a) * K];
  const bf16* Arow1 = &A [(size_t)(row0 + 64 + r_a) * K];
  const bf16* Brow0 = &Bt[(size_t)(col0      + r_a) * K];
  const bf16* Brow1 = &Bt[(size_t)(col0 + 64 + r_a) * K];
  av[0] = *(const uint4*)&Arow0[kc];
  av[1] = *(const uint4*)&Arow0[kc + 8];
  av[2] = *(const uint4*)&Arow1[kc];
  av[3] = *(const uint4*)&Arow1[kc + 8];
  bv[0] = *(const uint4*)&Brow0[kc];
  bv[1] = *(const uint4*)&Brow0[kc + 8];
  bv[2] = *(const uint4*)&Brow1[kc];
  bv[3] = *(const uint4*)&Brow1[kc + 8];
  for (int k0 = 0; k0 < K; k0 += 64) {
    __syncthreads();
    *(uint4*)&As[(     r_a)*72 + kc    ] = av[0];
    *(uint4*)&As[(     r_a)*72 + kc + 8] = av[1];
    *(uint4*)&As[(64 + r_a)*72 + kc    ] = av[2];
    *(uint4*)&As[(64 + r_a)*72 + kc + 8] = av[3];
    *(uint4*)&Bs[(     r_a)*72 + kc    ] = bv[0];
    *(uint4*)&Bs[(     r_a)*72 + kc + 8] = bv[1];
    *(uint4*)&Bs[(64 + r_a)*72 + kc    ] = bv[2];
    *(uint4*)&Bs[(64 + r_a)*72 + kc + 8] = bv[3];
    __syncthreads();
    int kn = k0 + 64;
    if (kn < K) {
      av[0] = *(const uint4*)&Arow0[kn + kc];
      av[1] = *(const uint4*)&Arow0[kn + kc + 8];
      av[2] = *(const uint4*)&Arow1[kn + kc];
      av[3] = *(const uint4*)&Arow1[kn + kc + 8];
      bv[0] = *(const uint4*)&Brow0[kn + kc];
      bv[1] = *(const uint4*)&Brow0[kn + kc + 8];
      bv[2] = *(const uint4*)&Brow1[kn + kc];
      bv[3] = *(const uint4*)&Brow1[kn + kc + 8];
    }
    #pragma unroll
    for (int kf = 0; kf < 2; ++kf) {
      bf16x8 af[4], bfv[4];
      #pragma unroll
      for (int i = 0; i < 4; ++i) af[i]  = *(const bf16x8*)&As[(wr + i*16 + m_l)*72 + kf*32 + quad*8];
      #pragma unroll
      for (int j = 0; j < 4; ++j) bfv[j] = *(const bf16x8*)&Bs[(wc + j*16 + m_l)*72 + kf*32 + quad*8];
      #pragma unroll
      for (int i = 0; i < 4; ++i)
        #pragma unroll
        for (int j = 0; j < 4; ++j)
          acc[i][j] = __builtin_amdgcn_mfma_f32_16x16x32_bf16(af[i], bfv[j], acc[i][j], 0, 0, 0);
    }
  }
  if (ADD) {
    // RMW epilogue (load allocates line -> writes measured exact)
    #pragma unroll
    for (int i = 0; i < 4; ++i)
      #pragma unroll
      for (int j = 0; j < 4; ++j) {
        int col = col0 + wc + j*16 + m_l;
        if (col < N) {
          #pragma unroll
          for (int r = 0; r < 4; ++r) {
            int row = row0 + wr + i*16 + quad*4 + r;
            C[(size_t)row*N + col] += acc[i][j][r];
          }
        }
      }
  } else if (OUTBF) {
    // stage bf16 tile (128x136) in LDS, then contiguous uint4 stores
    __syncthreads();
    bf16* bst = (bf16*)smem;
    #pragma unroll
    for (int i = 0; i < 4; ++i)
      #pragma unroll
      for (int j = 0; j < 4; ++j)
        #pragma unroll
        for (int r = 0; r < 4; ++r) {
          float v = acc[i][j][r];
          if (EPI == 1) { v = fmaxf(v, 0.f); v = v*v; }
          bst[(wr + i*16 + quad*4 + r)*136 + wc + j*16 + m_l] = f2b(v);
        }
    __syncthreads();
    for (int e = tid; e < 2048; e += 256) {
      int row = e >> 4, c8 = (e & 15) * 8;
      int gcol = col0 + c8;
      if (gcol < N)
        *(uint4*)&Cbf[(size_t)(row0 + row)*N + gcol] = *(uint4*)&bst[row*136 + c8];
    }
  } else {
    // fp32: stage in 2 half-tiles (64x132) then contiguous float4 stores
    float* fst = (float*)smem;
    #pragma unroll
    for (int half = 0; half < 2; ++half) {
      __syncthreads();
      if ((wave & 1) == half) {
        #pragma unroll
        for (int i = 0; i < 4; ++i)
          #pragma unroll
          for (int j = 0; j < 4; ++j)
            #pragma unroll
            for (int r = 0; r < 4; ++r) {
              float v = acc[i][j][r];
              if (EPI == 2) v = 1.f/(1.f + __expf(-v));
              fst[(i*16 + quad*4 + r)*132 + wc + j*16 + m_l] = v;
            }
      }
      __syncthreads();
      for (int e = tid; e < 2048; e += 256) {
        int row = e >> 5, c4 = (e & 31) * 4;
        int gcol = col0 + c4;
        if (gcol < N)
          *(float4*)&C[(size_t)(row0 + half*64 + row)*N + gcol] = *(float4*)&fst[row*132 + c4];
      }
    }
  }
}

// ---------------- MFMA GEMM 128x128 split-K: partials to workspace -----------
// Contiguous LDS-staged float4 partial stores (no scattered store-misses).
__global__ __launch_bounds__(256)
void mfma_sk(const bf16* __restrict__ A, const bf16* __restrict__ Bt,
             float* __restrict__ P0, float* __restrict__ P1,
             float* __restrict__ P2, float* __restrict__ P3,
             int M, int N, int K, int kchunk) {
  __shared__ __align__(16) char smem[36864];
  bf16* As = (bf16*)smem;
  bf16* Bs = (bf16*)(smem + 18432);
  int tid = threadIdx.x;
  int wave = tid >> 6, lane = tid & 63;
  int m_l = lane & 15, quad = lane >> 4;
  int wr = (wave & 1) * 64, wc = (wave >> 1) * 64;
  int row0 = blockIdx.y * 128, col0 = blockIdx.x * 128;
  int kbeg = blockIdx.z * kchunk;
  int kend = kbeg + kchunk;
  f32x4 acc[4][4];
  #pragma unroll
  for (int i = 0; i < 4; ++i)
    #pragma unroll
    for (int j = 0; j < 4; ++j) acc[i][j] = (f32x4){0.f,0.f,0.f,0.f};
  int r_a = tid >> 2;
  int kc  = (tid & 3) * 16;
  uint4 av[4], bv[4];
  const bf16* Arow0 = &A [(size_t)(row0      + r_a) * K];
  const bf16* Arow1 = &A [(size_t)(row0 + 64 + r_a) * K];
  const bf16* Brow0 = &Bt[(size_t)(col0      + r_a) * K];
  const bf16* Brow1 = &Bt[(size_t)(col0 + 64 + r_a) * K];
  av[0] = *(const uint4*)&Arow0[kbeg + kc];
  av[1] = *(const uint4*)&Arow0[kbeg + kc + 8];
  av[2] = *(const uint4*)&Arow1[kbeg + kc];
  av[3] = *(const uint4*)&Arow1[kbeg + kc + 8];
  bv[0] = *(const uint4*)&Brow0[kbeg + kc];
  bv[1] = *(const uint4*)&Brow0[kbeg + kc + 8];
  bv[2] = *(const uint4*)&Brow1[kbeg + kc];
  bv[3] = *(const uint4*)&Brow1[kbeg + kc + 8];
  for (int k0 = kbeg; k0 < kend; k0 += 64) {
    __syncthreads();
    *(uint4*)&As[(     r_a)*72 + kc    ] = av[0];
    *(uint4*)&As[(     r_a)*72 + kc + 8] = av[1];
    *(uint4*)&As[(64 + r_a)*72 + kc    ] = av[2];
    *(uint4*)&As[(64 + r_a)*72 + kc + 8] = av[3];
    *(uint4*)&Bs[(     r_a)*72 + kc    ] = bv[0];
    *(uint4*)&Bs[(     r_a)*72 + kc + 8] = bv[1];
    *(uint4*)&Bs[(64 + r_a)*72 + kc    ] = bv[2];
    *(uint4*)&Bs[(64 + r_a)*72 + kc + 8] = bv[3];
    __syncthreads();
    int kn = k0 + 64;
    if (kn < kend) {
      av[0] = *(const uint4*)&Arow0[kn + kc];
      av[1] = *(const uint4*)&Arow0[kn + kc + 8];
      av[2] = *(const uint4*)&Arow1[kn + kc];
      av[3] = *(const uint4*)&Arow1[kn + kc + 8];
      bv[0] = *(const uint4*)&Brow0[kn + kc];
      bv[1] = *(const uint4*)&Brow0[kn + kc + 8];
      bv[2] = *(const uint4*)&Brow1[kn + kc];
      bv[3] = *(const uint4*)&Brow1[kn + kc + 8];
    }
    #pragma unroll
    for (int kf = 0; kf < 2; ++kf) {
      bf16x8 af[4], bfv[4];
      #pragma unroll
      for (int i = 0; i < 4; ++i) af[i]  = *(const bf16x8*)&As[(wr + i*16 + m_l)*72 + kf*32 + quad*8];
      #pragma unroll
      for (int j = 0; j < 4; ++j) bfv[j] = *(const bf16x8*)&Bs[(wc + j*16 + m_l)*72 + kf*32 + quad*8];
      #pragma unroll
      for (int i = 0; i < 4; ++i)
        #pragma unroll
        for (int j = 0; j < 4; ++j)
          acc[i][j] = __builtin_amdgcn_mfma_f32_16x16x32_bf16(af[i], bfv[j], acc[i][j], 0, 0, 0);
    }
  }
  float* P = (blockIdx.z == 0) ? P0 : (blockIdx.z == 1) ? P1 : (blockIdx.z == 2) ? P2 : P3;
  float* fst = (float*)smem;
  #pragma unroll
  for (int half = 0; half < 2; ++half) {
    __syncthreads();
    if ((wave & 1) == half) {
      #pragma unroll
      for (int i = 0; i < 4; ++i)
        #pragma unroll
        for (int j = 0; j < 4; ++j)
          #pragma unroll
          for (int r = 0; r < 4; ++r)
            fst[(i*16 + quad*4 + r)*132 + wc + j*16 + m_l] = acc[i][j][r];
    }
    __syncthreads();
    for (int e = tid; e < 2048; e += 256) {
      int row = e >> 5, c4 = (e & 31) * 4;
      int gcol = col0 + c4;
      if (gcol < N)
        *(float4*)&P[(size_t)(row0 + half*64 + row)*N + gcol] = *(float4*)&fst[row*132 + c4];
    }
  }
}

// ---------------- split-K reduce: dst (+)= epi(sum of Z partials) ------------
template<int Z, int EPI, bool ADD>
__global__ void k_reduce(float* __restrict__ dst, const float* __restrict__ p0,
                         const float* __restrict__ p1, const float* __restrict__ p2,
                         const float* __restrict__ p3) {
  size_t i = ((size_t)blockIdx.x*256 + threadIdx.x)*4;
  float4 a = *(const float4*)(p0 + i);
  float4 b = *(const float4*)(p1 + i);
  float r0 = a.x + b.x, r1 = a.y + b.y, r2 = a.z + b.z, r3 = a.w + b.w;
  if (Z == 4) {
    float4 c = *(const float4*)(p2 + i);
    float4 d = *(const float4*)(p3 + i);
    r0 += c.x + d.x; r1 += c.y + d.y; r2 += c.z + d.z; r3 += c.w + d.w;
  }
  if (EPI == 2) {
    r0 = 1.f/(1.f + __expf(-r0)); r1 = 1.f/(1.f + __expf(-r1));
    r2 = 1.f/(1.f + __expf(-r2)); r3 = 1.f/(1.f + __expf(-r3));
  }
  if (ADD) {
    float4 o = *(const float4*)(dst + i);
    r0 += o.x; r1 += o.y; r2 += o.z; r3 += o.w;
  }
  float4 res; res.x = r0; res.y = r1; res.z = r2; res.w = r3;
  *(float4*)(dst + i) = res;
}

// ---------------- SSM conv (K=4) + silu + dt softplus; bf16 xBC out ----------
__global__ void k_conv_ssm(const float* __restrict__ ZXr, const float* __restrict__ cw,
                           const float* __restrict__ cb, const float* __restrict__ dtb,
                           bf16* __restrict__ XBCb, float* __restrict__ DT) {
  int bt = blockIdx.x; int b = bt >> 10; int t = bt & 1023;
  int tid = threadIdx.x;
  for (int c = tid; c < NXBC; c += 256) {
    float acc = cb[c];
    #pragma unroll
    for (int kk = 0; kk < 4; ++kk) {
      int ts = t - 3 + kk;
      if (ts >= 0) acc += cw[c*4+kk] * ZXr[((size_t)(b*TT+ts))*NXBCD + c];
    }
    float s = acc / (1.f + __expf(-acc));  // silu
    XBCb[(size_t)bt*NXBC + c] = f2b(s);
  }
  if (tid < NHS) {
    float x = ZXr[(size_t)bt*NXBCD + NXBC + tid] + dtb[tid];
    float sp = (x > 20.f) ? x : log1pf(__expf(x));
    DT[(size_t)bt*NHS + tid] = sp;
  }
}

// ---------------- scan pass 1: intra-chunk via MFMA (Mamba2 chunked) ---------
__global__ __launch_bounds__(256)
void k_scan1(const bf16* __restrict__ xbcb, const float* __restrict__ dt,
             const float* __restrict__ A_log, const float* __restrict__ Dmv,
             float* __restrict__ Y, float* __restrict__ SC, float* __restrict__ CUM) {
  int bc = blockIdx.x;
  int bh = bc >> 3, c = bc & 7;
  int b = bh >> 5, h = bh & 31;
  int tid = threadIdx.x, wave = tid >> 6, lane = tid & 63;
  int col = lane & 15, quad = lane >> 4;
  int t0 = c * CL;
  __shared__ bf16 sB[128*136];   // B rows [s][n]; later BwT [n][s]
  __shared__ bf16 sC[128*136];   // C rows [t][n]; later Ps [t][s]
  __shared__ bf16 sxT[64*136];   // x^T [p][t]
  __shared__ float sL[128], sdt[128];
  float A = -__expf(A_log[h]);
  float Dmh = Dmv[h];
  for (int e = tid; e < 128*16; e += 256) {
    int r = e >> 4, ch = e & 15;
    const bf16* row = xbcb + (size_t)(b*TT + t0 + r)*NXBC;
    *(uint4*)&sB[r*136 + ch*8] = *(const uint4*)&row[2048 + ch*8];
    *(uint4*)&sC[r*136 + ch*8] = *(const uint4*)&row[2176 + ch*8];
  }
  for (int e = tid; e < 64*128; e += 256) {
    int p = e & 63, t = e >> 6;
    sxT[p*136 + t] = xbcb[(size_t)(b*TT + t0 + t)*NXBC + h*64 + p];
  }
  if (tid < 128) sdt[tid] = dt[(size_t)(b*TT + t0 + tid)*NHS + h];
  __syncthreads();
  if (wave == 0) {
    float a0 = sdt[2*lane]*A, a1 = sdt[2*lane+1]*A;
    float tot = a0 + a1;
    #pragma unroll
    for (int off = 1; off < 64; off <<= 1) {
      float up = __shfl_up(tot, off);
      if (lane >= off) tot += up;
    }
    sL[2*lane+1] = tot;
    sL[2*lane]   = tot - a1;
  }
  __syncthreads();
  int wr = (wave & 1)*64, wc = (wave >> 1)*64;
  f32x4 g[4][4];
  #pragma unroll
  for (int i = 0; i < 4; ++i)
    #pragma unroll
    for (int j = 0; j < 4; ++j) g[i][j] = (f32x4){0.f,0.f,0.f,0.f};
  #pragma unroll
  for (int kf = 0; kf < 4; ++kf) {
    bf16x8 af[4], bfr[4];
    #pragma unroll
    for (int i = 0; i < 4; ++i) af[i]  = *(const bf16x8*)&sC[(wr + i*16 + col)*136 + kf*32 + quad*8];
    #pragma unroll
    for (int j = 0; j < 4; ++j) bfr[j] = *(const bf16x8*)&sB[(wc + j*16 + col)*136 + kf*32 + quad*8];
    #pragma unroll
    for (int i = 0; i < 4; ++i)
      #pragma unroll
      for (int j = 0; j < 4; ++j)
        g[i][j] = __builtin_amdgcn_mfma_f32_16x16x32_bf16(af[i], bfr[j], g[i][j], 0, 0, 0);
  }
  __syncthreads();
  if (tid < 128) CUM[(size_t)bh*TT + t0 + tid] = __expf(sL[tid]);
  float Lend = sL[127];
  #pragma unroll
  for (int i = 0; i < 4; ++i) {
    #pragma unroll
    for (int j = 0; j < 4; ++j) {
      int sl = wc + j*16 + col;
      #pragma unroll
      for (int r = 0; r < 4; ++r) {
        int tl = wr + i*16 + quad*4 + r;
        float v = (sl <= tl) ? g[i][j][r] * __expf(sL[tl] - sL[sl]) * sdt[sl] : 0.f;
        sC[tl*136 + sl] = f2b(v);
      }
    }
  }
  for (int e = tid; e < 128*128; e += 256) {
    int n = e & 127, s = e >> 7;
    float w = __expf(Lend - sL[s]) * sdt[s];
    sB[n*136 + s] = f2b(b2f(xbcb[(size_t)(b*TT + t0 + s)*NXBC + 2048 + n]) * w);
  }
  __syncthreads();
  f32x4 ya[2][4];
  #pragma unroll
  for (int i2 = 0; i2 < 2; ++i2)
    #pragma unroll
    for (int jd = 0; jd < 4; ++jd) ya[i2][jd] = (f32x4){0.f,0.f,0.f,0.f};
  #pragma unroll
  for (int kf = 0; kf < 4; ++kf) {
    bf16x8 pa[2], xa[4];
    #pragma unroll
    for (int i2 = 0; i2 < 2; ++i2)
      pa[i2] = *(const bf16x8*)&sC[(wave*32 + i2*16 + col)*136 + kf*32 + quad*8];
    #pragma unroll
    for (int jd = 0; jd < 4; ++jd)
      xa[jd] = *(const bf16x8*)&sxT[(jd*16 + col)*136 + kf*32 + quad*8];
    #pragma unroll
    for (int i2 = 0; i2 < 2; ++i2)
      #pragma unroll
      for (int jd = 0; jd < 4; ++jd)
        ya[i2][jd] = __builtin_amdgcn_mfma_f32_16x16x32_bf16(pa[i2], xa[jd], ya[i2][jd], 0, 0, 0);
  }
  #pragma unroll
  for (int i2 = 0; i2 < 2; ++i2) {
    #pragma unroll
    for (int jd = 0; jd < 4; ++jd) {
      int p = jd*16 + col;
      #pragma unroll
      for (int r = 0; r < 4; ++r) {
        int tl = wave*32 + i2*16 + quad*4 + r;
        float xv = b2f(sxT[p*136 + tl]);
        Y[(size_t)(b*TT + t0 + tl)*DI + h*64 + p] = ya[i2][jd][r] + xv*Dmh;
      }
    }
  }
  f32x4 sa[8];
  #pragma unroll
  for (int nt = 0; nt < 8; ++nt) sa[nt] = (f32x4){0.f,0.f,0.f,0.f};
  #pragma unroll
  for (int kf = 0; kf < 4; ++kf) {
    bf16x8 xpa = *(const bf16x8*)&sxT[(wave*16 + col)*136 + kf*32 + quad*8];
    #pragma unroll
    for (int nt = 0; nt < 8; ++nt) {
      bf16x8 bwa = *(const bf16x8*)&sB[(nt*16 + col)*136 + kf*32 + quad*8];
      sa[nt] = __builtin_amdgcn_mfma_f32_16x16x32_bf16(xpa, bwa, sa[nt], 0, 0, 0);
    }
  }
  #pragma unroll
  for (int nt = 0; nt < 8; ++nt) {
    int n = nt*16 + col;
    #pragma unroll
    for (int r = 0; r < 4; ++r) {
      int p = wave*16 + quad*4 + r;
      SC[((size_t)(bh*NC + c)*64 + p)*128 + n] = sa[nt][r];
    }
  }
}

// ---------------- scan pass 2: sequential inter-chunk combine (fp32) ---------
__global__ __launch_bounds__(512)
void k_scan2(float* __restrict__ SC, const float* __restrict__ CUM) {
  int bh = blockIdx.x;
  int tid = threadIdx.x;
  int p = tid >> 3, g = tid & 7;
  float S[16];
  #pragma unroll
  for (int j = 0; j < 16; ++j) S[j] = 0.f;
  for (int c = 0; c < NC; ++c) {
    size_t base = ((size_t)(bh*NC + c)*64 + p)*128 + g*16;
    float Ptot = CUM[(size_t)bh*TT + c*CL + (CL-1)];
    float tmp[16];
    #pragma unroll
    for (int j = 0; j < 16; ++j) tmp[j] = SC[base + j];
    #pragma unroll
    for (int j = 0; j < 16; ++j) SC[base + j] = S[j];
    #pragma unroll
    for (int j = 0; j < 16; ++j) S[j] = S[j]*Ptot + tmp[j];
  }
}

// ---------------- scan pass 3: Y += CUM[t] * (C @ S_init^T) via MFMA ---------
__global__ __launch_bounds__(256)
void k_scan3(const bf16* __restrict__ xbcb, const float* __restrict__ SC,
             const float* __restrict__ CUM, float* __restrict__ Y) {
  int bc = blockIdx.x;
  int bh = bc >> 3, c = bc & 7;
  if (c == 0) return;
  int b = bh >> 5, h = bh & 31;
  int tid = threadIdx.x, wave = tid >> 6, lane = tid & 63;
  int col = lane & 15, quad = lane >> 4;
  int t0 = c * CL;
  __shared__ bf16 sCt[128*136];
  __shared__ bf16 sS[64*136];
  __shared__ float sCum[128];
  for (int e = tid; e < 128*16; e += 256) {
    int r = e >> 4, ch = e & 15;
    *(uint4*)&sCt[r*136 + ch*8] =
      *(const uint4*)&xbcb[(size_t)(b*TT + t0 + r)*NXBC + 2176 + ch*8];
  }
  for (int e = tid; e < 64*128; e += 256) {
    int n = e & 127, p = e >> 7;
    sS[p*136 + n] = f2b(SC[((size_t)(bh*NC + c)*64 + p)*128 + n]);
  }
  if (tid < 128) sCum[tid] = CUM[(size_t)bh*TT + t0 + tid];
  __syncthreads();
  f32x4 ya[2][4];
  #pragma unroll
  for (int i2 = 0; i2 < 2; ++i2)
    #pragma unroll
    for (int jd = 0; jd < 4; ++jd) ya[i2][jd] = (f32x4){0.f,0.f,0.f,0.f};
  #pragma unroll
  for (int kf = 0; kf < 4; ++kf) {
    bf16x8 pa[2], sv[4];
    #pragma unroll
    for (int i2 = 0; i2 < 2; ++i2)
      pa[i2] = *(const bf16x8*)&sCt[(wave*32 + i2*16 + col)*136 + kf*32 + quad*8];
    #pragma unroll
    for (int jd = 0; jd < 4; ++jd)
      sv[jd] = *(const bf16x8*)&sS[(jd*16 + col)*136 + kf*32 + quad*8];
    #pragma unroll
    for (int i2 = 0; i2 < 2; ++i2)
      #pragma unroll
      for (int jd = 0; jd < 4; ++jd)
        ya[i2][jd] = __builtin_amdgcn_mfma_f32_16x16x32_bf16(pa[i2], sv[jd], ya[i2][jd], 0, 0, 0);
  }
  #pragma unroll
  for (int i2 = 0; i2 < 2; ++i2) {
    #pragma unroll
    for (int jd = 0; jd < 4; ++jd) {
      int p = jd*16 + col;
      #pragma unroll
      for (int r = 0; r < 4; ++r) {
        int tl = wave*32 + i2*16 + quad*4 + r;
        Y[(size_t)(b*TT + t0 + tl)*DI + h*64 + p] += sCum[tl]*ya[i2][jd][r];
      }
    }
  }
}

// ---------------- gate: Ybf = bf16(rmsnorm(y * silu(z)) * mnorm_w) -----------
__global__ void k_gate(const float* __restrict__ Y, const float* __restrict__ Z,
                       const float* __restrict__ mnw, bf16* __restrict__ Ybf) {
  int row = blockIdx.x; int tid = threadIdx.x;
  const float* yr = Y + (size_t)row*DI;
  const float* zr = Z + (size_t)row*DI;
  float gv[8]; float ss = 0.f;
  #pragma unroll
  for (int i = 0; i < 8; ++i) {
    int c = tid*8 + i;
    float z = zr[c];
    float sz = z / (1.f + __expf(-z));
    float v = yr[c]*sz;
    gv[i] = v; ss += v*v;
  }
  __shared__ float red[256];
  red[tid] = ss; __syncthreads();
  for (int s = 128; s > 0; s >>= 1) { if (tid < s) red[tid] += red[tid+s]; __syncthreads(); }
  float scale = rsqrtf(red[0]/(float)DI + 1e-5f);
  bf16* br = Ybf + (size_t)row*DI;
  #pragma unroll
  for (int i = 0; i < 8; ++i) { int c = tid*8 + i; br[c] = f2b(gv[i]*scale*mnw[c]); }
}

// ---------------- q/k/v causal dwconv (K=3), bf16 out, Q pre-scaled, V^T -----
__global__ void k_conv_qkv(const float* __restrict__ QKV,
                           const float* qw, const float* qb, const float* kw, const float* kb,
                           const float* vw, const float* vb,
                           bf16* __restrict__ Qb, bf16* __restrict__ Kb, bf16* __restrict__ Vtb) {
  int bt = blockIdx.x; int b = bt >> 10; int t = bt & 1023;
  int tid = threadIdx.x;
  for (int c = tid; c < 1152; c += 256) {
    if (c < 1024) {
      int h = c >> 6, d = c & 63;
      float acc = qb[d];
      #pragma unroll
      for (int kk = 0; kk < 3; ++kk) { int ts = t-2+kk; if (ts >= 0) acc += qw[d*3+kk] * QKV[((size_t)(b*TT+ts))*1152 + c]; }
      Qb[((size_t)(b*NHA + h)*TT + t)*HD + d] = f2b(acc * 0.125f);  // 1/sqrt(64)
    } else if (c < 1088) {
      int d = c - 1024;
      float acc = kb[d];
      #pragma unroll
      for (int kk = 0; kk < 3; ++kk) { int ts = t-2+kk; if (ts >= 0) acc += kw[d*3+kk] * QKV[((size_t)(b*TT+ts))*1152 + c]; }
      Kb[(size_t)bt*HD + d] = f2b(acc);
    } else {
      int d = c - 1088;
      float acc = vb[d];
      #pragma unroll
      for (int kk = 0; kk < 3; ++kk) { int ts = t-2+kk; if (ts >= 0) acc += vw[d*3+kk] * QKV[((size_t)(b*TT+ts))*1152 + c]; }
      Vtb[((size_t)(b*HD + d))*TT + t] = f2b(acc);
    }
  }
}

// ---------------- MFMA flash attention ---------------------------------------
__global__ __launch_bounds__(256)
void k_flash(const bf16* __restrict__ Qb, const bf16* __restrict__ Kb,
             const bf16* __restrict__ Vtb, bf16* __restrict__ out) {
  int qt = blockIdx.x, h = blockIdx.y, b = blockIdx.z;
  int tid = threadIdx.x, wave = tid >> 6, lane = tid & 63;
  int col = lane & 15, quad = lane >> 4;
  int t0 = qt * 128;
  __shared__ bf16 Ks[128*72];
  __shared__ bf16 Vs[64*136];
  __shared__ bf16 Ps[4][32*136];
  const bf16* Qbase = Qb + ((size_t)(b*NHA + h))*TT*HD;
  bf16x8 qf[2][2];
  #pragma unroll
  for (int i = 0; i < 2; ++i)
    #pragma unroll
    for (int kf = 0; kf < 2; ++kf)
      qf[i][kf] = *(const bf16x8*)&Qbase[(size_t)(t0 + wave*32 + i*16 + col)*HD + kf*32 + quad*8];
  float mst[2][4], lst[2][4];
  f32x4 oacc[2][4];
  #pragma unroll
  for (int i = 0; i < 2; ++i)
    #pragma unroll
    for (int r = 0; r < 4; ++r) { mst[i][r] = -1e30f; lst[i][r] = 0.f; }
  #pragma unroll
  for (int i = 0; i < 2; ++i)
    #pragma unroll
    for (int jd = 0; jd < 4; ++jd) oacc[i][jd] = (f32x4){0.f,0.f,0.f,0.f};

  for (int kt = 0; kt <= qt; ++kt) {
    int s0 = kt * 128;
    __syncthreads();
    for (int e = tid; e < 1024; e += 256) {
      int r = e >> 3, ch = e & 7;
      *(uint4*)&Ks[r*72 + ch*8] = *(const uint4*)&Kb[((size_t)(b*TT + s0 + r))*HD + ch*8];
    }
    for (int e = tid; e < 1024; e += 256) {
      int d = e >> 4, ch = e & 15;
      *(uint4*)&Vs[d*136 + ch*8] = *(const uint4*)&Vtb[((size_t)(b*HD + d))*TT + s0 + ch*8];
    }
    __syncthreads();
    f32x4 sacc[2][8];
    #pragma unroll
    for (int i = 0; i < 2; ++i)
      #pragma unroll
      for (int j = 0; j < 8; ++j) sacc[i][j] = (f32x4){0.f,0.f,0.f,0.f};
    #pragma unroll
    for (int j = 0; j < 8; ++j) {
      bf16x8 kf0 = *(const bf16x8*)&Ks[(j*16 + col)*72 + quad*8];
      bf16x8 kf1 = *(const bf16x8*)&Ks[(j*16 + col)*72 + 32 + quad*8];
      #pragma unroll
      for (int i = 0; i < 2; ++i) {
        sacc[i][j] = __builtin_amdgcn_mfma_f32_16x16x32_bf16(qf[i][0], kf0, sacc[i][j], 0, 0, 0);
        sacc[i][j] = __builtin_amdgcn_mfma_f32_16x16x32_bf16(qf[i][1], kf1, sacc[i][j], 0, 0, 0);
      }
    }
    bool diag = (kt == qt);
    #pragma unroll
    for (int i = 0; i < 2; ++i) {
      #pragma unroll
      for (int r = 0; r < 4; ++r) {
        int rowloc = wave*32 + i*16 + quad*4 + r;
        if (diag) {
          #pragma unroll
          for (int j = 0; j < 8; ++j)
            if (j*16 + col > rowloc) sacc[i][j][r] = -1e30f;
        }
        float mx = -1e30f;
        #pragma unroll
        for (int j = 0; j < 8; ++j) mx = fmaxf(mx, sacc[i][j][r]);
        mx = fmaxf(mx, __shfl_xor(mx, 1));
        mx = fmaxf(mx, __shfl_xor(mx, 2));
        mx = fmaxf(mx, __shfl_xor(mx, 4));
        mx = fmaxf(mx, __shfl_xor(mx, 8));
        float nm = fmaxf(mst[i][r], mx);
        float alpha = __expf(mst[i][r] - nm);
        float sum = 0.f;
        #pragma unroll
        for (int j = 0; j < 8; ++j) {
          float pv = __expf(sacc[i][j][r] - nm);
          sacc[i][j][r] = pv; sum += pv;
        }
        sum += __shfl_xor(sum, 1);
        sum += __shfl_xor(sum, 2);
        sum += __shfl_xor(sum, 4);
        sum += __shfl_xor(sum, 8);
        lst[i][r] = lst[i][r]*alpha + sum;
        mst[i][r] = nm;
        #pragma unroll
        for (int jd = 0; jd < 4; ++jd) oacc[i][jd][r] *= alpha;
      }
    }
    #pragma unroll
    for (int i = 0; i < 2; ++i)
      #pragma unroll
      for (int j = 0; j < 8; ++j)
        #pragma unroll
        for (int r = 0; r < 4; ++r)
          Ps[wave][(i*16 + quad*4 + r)*136 + j*16 + col] = f2b(sacc[i][j][r]);
    #pragma unroll
    for (int i = 0; i < 2; ++i) {
      bf16x8 pa[4];
      #pragma unroll
      for (int kf = 0; kf < 4; ++kf)
        pa[kf] = *(const bf16x8*)&Ps[wave][(i*16 + col)*136 + kf*32 + quad*8];
      #pragma unroll
      for (int jd = 0; jd < 4; ++jd) {
        #pragma unroll
        for (int kf = 0; kf < 4; ++kf) {
          bf16x8 vbf = *(const bf16x8*)&Vs[(jd*16 + col)*136 + kf*32 + quad*8];
          oacc[i][jd] = __builtin_amdgcn_mfma_f32_16x16x32_bf16(pa[kf], vbf, oacc[i][jd], 0, 0, 0);
        }
      }
    }
  }
  #pragma unroll
  for (int i = 0; i < 2; ++i) {
    #pragma unroll
    for (int jd = 0; jd < 4; ++jd) {
      int d = jd*16 + col;
      #pragma unroll
      for (int r = 0; r < 4; ++r) {
        int t = t0 + wave*32 + i*16 + quad*4 + r;
        out[((size_t)(b*TT + t))*DM + h*64 + d] = f2b(oacc[i][jd][r] / lst[i][r]);
      }
    }
  }
}

// ---------------- token shift (bf16 in/out) ----------------------------------
__global__ void k_tshift(const bf16* __restrict__ H, const float* __restrict__ maak,
                         const float* __restrict__ maar,
                         bf16* __restrict__ XK, bf16* __restrict__ XR) {
  int idx = blockIdx.x*256 + threadIdx.x;
  int c = idx & (DM - 1);
  int bt = idx >> 10;
  int t = bt & (TT - 1);
  float h = b2f(H[idx]);
  float prev = (t > 0) ? b2f(H[idx - DM]) : 0.f;
  float xx = prev - h;
  XK[idx] = f2b(h + xx*maak[c]);
  XR[idx] = f2b(h + xx*maar[c]);
}

// ---------------- final: out = x + sigmoid_r * kv ----------------------------
__global__ void k_final(const float* __restrict__ X, const float* __restrict__ R,
                        const float* __restrict__ KV, float* __restrict__ out) {
  int idx = blockIdx.x*256 + threadIdx.x;
  out[idx] = X[idx] + R[idx]*KV[idx];
}

// =============================================================================
extern "C" void kernel_launch(void* const* d_in, const int* in_sizes, int n_in,
                              void* d_out, int out_size, void* d_ws, size_t ws_size,
                              hipStream_t stream) {
  const float* x_in    = (const float*)d_in[0];
  const float* W_in    = (const float*)d_in[1];
  const float* conv_w  = (const float*)d_in[2];
  const float* conv_b  = (const float*)d_in[3];
  const float* A_log   = (const float*)d_in[4];
  const float* Dm      = (const float*)d_in[5];
  const float* dt_bias = (const float*)d_in[6];
  const float* mnorm_w = (const float*)d_in[7];
  const float* W_out   = (const float*)d_in[8];
  const float* W_qkv   = (const float*)d_in[9];
  const float* W_cproj = (const float*)d_in[10];
  const float* qconv_w = (const float*)d_in[11];
  const float* qconv_b = (const float*)d_in[12];
  const float* kconv_w = (const float*)d_in[13];
  const float* kconv_b = (const float*)d_in[14];
  const float* vconv_w = (const float*)d_in[15];
  const float* vconv_b = (const float*)d_in[16];
  const float* maa_k   = (const float*)d_in[17];
  const float* maa_r   = (const float*)d_in[18];
  const float* W_key   = (const float*)d_in[19];
  const float* W_rec   = (const float*)d_in[20];
  const float* W_val   = (const float*)d_in[21];
  float* out = (float*)d_out;

  float* ws = (float*)d_ws;
  float* X       = ws;                       // [0, 2,097,152)
  bf16*  Hbf     = (bf16*)(ws + 2097152);    // 2,097,152 bf16
  float* Zbuf    = ws + 3145728;             // [3,145,728, 7,340,032)
  float* XBCDraw = ws + 7340032;             // [7,340,032, 12,124,160)
  float* XBC     = ws + 12124160;            // [12,124,160, 16,842,752)
  float* DT      = ws + 16842752;            // +65,536
  float* CUM     = ws + 16908288;            // +65,536
  float* Y       = ws + 16973824;            // [16,973,824, 21,168,128)

  bf16*  Wt_in    = (bf16*)XBC;
  bf16*  XBCb     = (bf16*)XBC;
  float* SC       = XBCDraw;
  bf16*  Ybf      = (bf16*)XBC;
  bf16*  Wt_out   = (bf16*)(XBC + 2097152);
  float* QKV      = Zbuf;
  bf16*  Wt_qkv   = (bf16*)XBC;
  bf16*  Qb       = (bf16*)XBCDraw;
  bf16*  Kb       = (bf16*)(XBCDraw + 1048576);
  bf16*  Vtb      = (bf16*)(XBCDraw + 1114112);
  bf16*  ATTNbf   = (bf16*)Y;
  bf16*  Wt_cproj = (bf16*)(Y + 1048576);
  bf16*  XKbf     = (bf16*)XBC;
  bf16*  XRbf     = (bf16*)(XBC + 1048576);
  bf16*  Wt_key   = (bf16*)Zbuf;
  bf16*  KFbf     = (bf16*)XBCDraw;
  bf16*  Wt_val   = (bf16*)Zbuf;
  float* KV       = Y;
  float* R        = Y + 2097152;
  bf16*  Wt_rec   = (bf16*)Zbuf;

  dim3 thr256(256), thr512(512);
  dim3 tblk(32, 8);

  // 1. X = x; Hbf = rmsnorm(x)
  k_rms_in<<<BT, thr256, 0, stream>>>(x_in, X, Hbf);
  // 2. [Z | XBCDraw] = Hbf @ W_in  (wide, full-K, staged fp32 epilogue)
  k_tcast<<<dim3(4480/32, 1024/32), tblk, 0, stream>>>(W_in, Wt_in, 1024, NZX);
  mfma_gemm<0,false,false><<<dim3(16, 16), thr256, 0, stream>>>(Hbf, Wt_in, Zbuf, nullptr, BT, 2048, 1024);
  mfma_gemm<0,false,false><<<dim3(19, 16), thr256, 0, stream>>>(Hbf, Wt_in + (size_t)2048*1024, XBCDraw, nullptr, BT, NXBCD, 1024);
  // 3. conv+silu on xBC (bf16 out), softplus dt
  k_conv_ssm<<<BT, thr256, 0, stream>>>(XBCDraw, conv_w, conv_b, dt_bias, XBCb, DT);
  // 4. SSM chunked scan via MFMA
  k_scan1<<<BB*NHS*NC, thr256, 0, stream>>>(XBCb, DT, A_log, Dm, Y, SC, CUM);
  k_scan2<<<BB*NHS, thr512, 0, stream>>>(SC, CUM);
  k_scan3<<<BB*NHS*NC, thr256, 0, stream>>>(XBCb, SC, CUM, Y);
  // 5. gate + mnorm -> Ybf
  k_gate<<<BT, thr256, 0, stream>>>(Y, Zbuf, mnorm_w, Ybf);
  // 6. X += Ybf @ W_out  (split-K z=4 -> 512 blocks; staged partials)
  k_tcast<<<dim3(1024/32, 2048/32), tblk, 0, stream>>>(W_out, Wt_out, 2048, 1024);
  mfma_sk<<<dim3(8, 16, 4), thr256, 0, stream>>>(Ybf, Wt_out,
      Zbuf, Zbuf + 2097152, XBCDraw, XBCDraw + 2097152, BT, 1024, 2048, 512);
  k_reduce<4,0,true><<<2048, thr256, 0, stream>>>(X, Zbuf, Zbuf + 2097152, XBCDraw, XBCDraw + 2097152);
  // 7. Hbf = rmsnorm(X)
  k_rms_f32<<<BT, thr256, 0, stream>>>(X, Hbf);
  // 8. QKV = Hbf @ W_qkv  (split-K z=2 -> 288 blocks)
  k_tcast<<<dim3(1152/32, 1024/32), tblk, 0, stream>>>(W_qkv, Wt_qkv, 1024, 1152);
  mfma_sk<<<dim3(9, 16, 2), thr256, 0, stream>>>(Hbf, Wt_qkv,
      XBCDraw, XBCDraw + 2359296, XBCDraw, XBCDraw, BT, 1152, 1024, 512);
  k_reduce<2,0,false><<<2304, thr256, 0, stream>>>(QKV, XBCDraw, XBCDraw + 2359296, XBCDraw, XBCDraw);
  // 9. q/k/v convs -> bf16 Qb (scaled), Kb, Vtb (transposed)
  k_conv_qkv<<<BT, thr256, 0, stream>>>(QKV, qconv_w, qconv_b, kconv_w, kconv_b, vconv_w, vconv_b, Qb, Kb, Vtb);
  // 10. MFMA flash attention -> ATTNbf
  k_flash<<<dim3(TT/128, NHA, BB), thr256, 0, stream>>>(Qb, Kb, Vtb, ATTNbf);
  // 11. X += ATTNbf @ W_cproj  (split-K z=2 -> 256 blocks)
  k_tcast<<<dim3(1024/32, 1024/32), tblk, 0, stream>>>(W_cproj, Wt_cproj, 1024, 1024);
  mfma_sk<<<dim3(8, 16, 2), thr256, 0, stream>>>(ATTNbf, Wt_cproj,
      XBC, XBC + 2097152, XBC, XBC, BT, 1024, 1024, 512);
  k_reduce<2,0,true><<<2048, thr256, 0, stream>>>(X, XBC, XBC + 2097152, XBC, XBC);
  // 12. Hbf = rmsnorm(X)
  k_rms_f32<<<BT, thr256, 0, stream>>>(X, Hbf);
  // 13. token shift -> XKbf, XRbf
  k_tshift<<<(BT*DM)/256, thr256, 0, stream>>>(Hbf, maa_k, maa_r, XKbf, XRbf);
  // 14. KFbf = bf16(relu(XKbf @ W_key)^2)  (wide, full-K, staged bf16 epilogue)
  k_tcast<<<dim3(4096/32, 1024/32), tblk, 0, stream>>>(W_key, Wt_key, 1024, 4096);
  mfma_gemm<1,false,true><<<dim3(32, 16), thr256, 0, stream>>>(XKbf, Wt_key, nullptr, KFbf, BT, 4096, 1024);
  // 15. KV = KFbf @ W_val  (split-K z=4 -> 512 blocks)
  k_tcast<<<dim3(1024/32, 4096/32), tblk, 0, stream>>>(W_val, Wt_val, 4096, 1024);
  mfma_sk<<<dim3(8, 16, 4), thr256, 0, stream>>>(KFbf, Wt_val,
      Y, Y + 2097152, XBC + 2621440, Zbuf + 2097152, BT, 1024, 4096, 1024);
  k_reduce<4,0,false><<<2048, thr256, 0, stream>>>(KV, Y, Y + 2097152, XBC + 2621440, Zbuf + 2097152);
  // 16. R = sigmoid(XRbf @ W_rec)  (split-K z=2 -> 256 blocks)
  k_tcast<<<dim3(1024/32, 1024/32), tblk, 0, stream>>>(W_rec, Wt_rec, 1024, 1024);
  mfma_sk<<<dim3(8, 16, 2), thr256, 0, stream>>>(XRbf, Wt_rec,
      Y + 2097152, XBC + 2621440, Y, Y, BT, 1024, 1024, 512);
  k_reduce<2,2,false><<<2048, thr256, 0, stream>>>(R, Y + 2097152, XBC + 2621440, Y, Y);
  // 17. out = x + sigmoid_r * kv
  k_final<<<(BT*DM)/256, thr256, 0, stream>>>(X, R, KV, out);
}

// Round 11
// 592.676 us; speedup vs baseline: 1.4161x; 1.4161x over previous
//
#include <hip/hip_runtime.h>
#include <hip/hip_bf16.h>
#include <math.h>

#define BB 2
#define TT 1024
#define BT (BB*TT)          // 2048 rows
#define DM 1024
#define DI 2048
#define DS 128
#define NHS 32              // ssm heads
#define PDIM 64             // ssm headdim
#define NHA 16              // attn heads
#define HD 64
#define FFN_ 4096
#define NZX 4384            // 2*DI + 2*DS + NHS
#define NXBC 2304           // DI + 2*DS
#define NXBCD 2336          // xBC (2304) + dt (32) raw gemm-out width
#define CL 128              // scan chunk length
#define NC 8                // chunks

typedef __hip_bfloat16 bf16;
typedef short bf16x8 __attribute__((ext_vector_type(8)));
typedef float f32x4 __attribute__((ext_vector_type(4)));

__device__ __forceinline__ float b2f(bf16 v){ return __bfloat162float(v); }
__device__ __forceinline__ bf16 f2b(float v){ return __float2bfloat16(v); }

// ---------------- RMSNorm: write fp32 X copy + bf16 normalized H -------------
__global__ void k_rms_in(const float* __restrict__ xin, float* __restrict__ X,
                         bf16* __restrict__ H) {
  int row = blockIdx.x;
  int tid = threadIdx.x;          // 256 threads, 4 elems each (DM=1024)
  const float* xr = xin + (size_t)row * DM;
  float v[4]; float ss = 0.f;
  #pragma unroll
  for (int i = 0; i < 4; ++i) { v[i] = xr[tid*4+i]; ss += v[i]*v[i]; }
  __shared__ float red[256];
  red[tid] = ss; __syncthreads();
  for (int s = 128; s > 0; s >>= 1) { if (tid < s) red[tid] += red[tid+s]; __syncthreads(); }
  float scale = rsqrtf(red[0]/(float)DM + 1e-6f);
  float* Xr = X + (size_t)row*DM; bf16* Hr = H + (size_t)row*DM;
  #pragma unroll
  for (int i = 0; i < 4; ++i) { Xr[tid*4+i] = v[i]; Hr[tid*4+i] = f2b(v[i]*scale); }
}

__global__ void k_rms_f32(const float* __restrict__ X, bf16* __restrict__ H) {
  int row = blockIdx.x;
  int tid = threadIdx.x;
  const float* xr = X + (size_t)row * DM;
  float v[4]; float ss = 0.f;
  #pragma unroll
  for (int i = 0; i < 4; ++i) { v[i] = xr[tid*4+i]; ss += v[i]*v[i]; }
  __shared__ float red[256];
  red[tid] = ss; __syncthreads();
  for (int s = 128; s > 0; s >>= 1) { if (tid < s) red[tid] += red[tid+s]; __syncthreads(); }
  float scale = rsqrtf(red[0]/(float)DM + 1e-6f);
  bf16* Hr = H + (size_t)row*DM;
  #pragma unroll
  for (int i = 0; i < 4; ++i) Hr[tid*4+i] = f2b(v[i]*scale);
}

// ---------------- weight cast + transpose: Wt[n][k] = bf16(W[k][n]) ----------
__global__ void k_tcast(const float* __restrict__ W, bf16* __restrict__ Wt,
                        int K, int N) {
  __shared__ float t[32][33];
  int tx = threadIdx.x, ty = threadIdx.y;
  int n0 = blockIdx.x*32, k0 = blockIdx.y*32;
  #pragma unroll
  for (int i = 0; i < 4; ++i) {
    int k = k0 + ty + i*8, n = n0 + tx;
    t[ty + i*8][tx] = (n < N) ? W[(size_t)k*N + n] : 0.f;
  }
  __syncthreads();
  #pragma unroll
  for (int i = 0; i < 4; ++i) {
    int n = n0 + ty + i*8, k = k0 + tx;
    Wt[(size_t)n*K + k] = f2b(t[tx][ty + i*8]);
  }
}

// ---------------- MFMA GEMM 128x128, BK=32 (round-6 proven loop) -------------
template<int EPI, bool ADD, bool OUTBF>
__global__ __launch_bounds__(256)
void mfma_gemm(const bf16* __restrict__ A, const bf16* __restrict__ Bt,
               float* __restrict__ C, bf16* __restrict__ Cbf,
               int M, int N, int K) {
  __shared__ bf16 As[128*32];
  __shared__ bf16 Bs[128*32];
  int tid = threadIdx.x;
  int wave = tid >> 6, lane = tid & 63;
  int m_l = lane & 15, quad = lane >> 4;
  int wr = (wave & 1) * 64, wc = (wave >> 1) * 64;
  int row0 = blockIdx.y * 128, col0 = blockIdx.x * 128;
  f32x4 acc[4][4];
  #pragma unroll
  for (int i = 0; i < 4; ++i)
    #pragma unroll
    for (int j = 0; j < 4; ++j) acc[i][j] = (f32x4){0.f,0.f,0.f,0.f};
  int r_a = tid >> 2;            // 0..63
  int kc  = (tid & 3) * 8;       // 0,8,16,24
  for (int k0 = 0; k0 < K; k0 += 32) {
    uint4 av0 = *(const uint4*)&A [(size_t)(row0      + r_a) * K + k0 + kc];
    uint4 av1 = *(const uint4*)&A [(size_t)(row0 + 64 + r_a) * K + k0 + kc];
    uint4 bv0 = *(const uint4*)&Bt[(size_t)(col0      + r_a) * K + k0 + kc];
    uint4 bv1 = *(const uint4*)&Bt[(size_t)(col0 + 64 + r_a) * K + k0 + kc];
    __syncthreads();
    *(uint4*)&As[(     r_a) * 32 + kc] = av0;
    *(uint4*)&As[(64 + r_a) * 32 + kc] = av1;
    *(uint4*)&Bs[(     r_a) * 32 + kc] = bv0;
    *(uint4*)&Bs[(64 + r_a) * 32 + kc] = bv1;
    __syncthreads();
    bf16x8 af[4], bfv[4];
    #pragma unroll
    for (int i = 0; i < 4; ++i) af[i]  = *(const bf16x8*)&As[(wr + i*16 + m_l)*32 + quad*8];
    #pragma unroll
    for (int j = 0; j < 4; ++j) bfv[j] = *(const bf16x8*)&Bs[(wc + j*16 + m_l)*32 + quad*8];
    #pragma unroll
    for (int i = 0; i < 4; ++i)
      #pragma unroll
      for (int j = 0; j < 4; ++j)
        acc[i][j] = __builtin_amdgcn_mfma_f32_16x16x32_bf16(af[i], bfv[j], acc[i][j], 0, 0, 0);
  }
  #pragma unroll
  for (int i = 0; i < 4; ++i) {
    #pragma unroll
    for (int j = 0; j < 4; ++j) {
      int col = col0 + wc + j*16 + m_l;
      if (col < N) {
        #pragma unroll
        for (int r = 0; r < 4; ++r) {
          int row = row0 + wr + i*16 + quad*4 + r;
          float v = acc[i][j][r];
          if (EPI == 1) { v = fmaxf(v, 0.f); v = v*v; }          // relu^2
          else if (EPI == 2) v = 1.f/(1.f + __expf(-v));          // sigmoid
          if (OUTBF)      Cbf[(size_t)row*N + col] = f2b(v);
          else if (ADD)   C[(size_t)row*N + col] += v;
          else            C[(size_t)row*N + col]  = v;
        }
      }
    }
  }
}

// ---------------- split-K GEMM, BK=32 loop, partial stores -------------------
// grid (N/128, M/128, Z); z covers K range [z*kchunk, (z+1)*kchunk).
__global__ __launch_bounds__(256)
void mfma_sk32(const bf16* __restrict__ A, const bf16* __restrict__ Bt,
               float* __restrict__ P0, float* __restrict__ P1,
               float* __restrict__ P2, float* __restrict__ P3,
               int M, int N, int K, int kchunk) {
  __shared__ bf16 As[128*32];
  __shared__ bf16 Bs[128*32];
  int tid = threadIdx.x;
  int wave = tid >> 6, lane = tid & 63;
  int m_l = lane & 15, quad = lane >> 4;
  int wr = (wave & 1) * 64, wc = (wave >> 1) * 64;
  int row0 = blockIdx.y * 128, col0 = blockIdx.x * 128;
  int kbeg = blockIdx.z * kchunk;
  int kend = kbeg + kchunk;
  f32x4 acc[4][4];
  #pragma unroll
  for (int i = 0; i < 4; ++i)
    #pragma unroll
    for (int j = 0; j < 4; ++j) acc[i][j] = (f32x4){0.f,0.f,0.f,0.f};
  int r_a = tid >> 2;            // 0..63
  int kc  = (tid & 3) * 8;       // 0,8,16,24
  for (int k0 = kbeg; k0 < kend; k0 += 32) {
    uint4 av0 = *(const uint4*)&A [(size_t)(row0      + r_a) * K + k0 + kc];
    uint4 av1 = *(const uint4*)&A [(size_t)(row0 + 64 + r_a) * K + k0 + kc];
    uint4 bv0 = *(const uint4*)&Bt[(size_t)(col0      + r_a) * K + k0 + kc];
    uint4 bv1 = *(const uint4*)&Bt[(size_t)(col0 + 64 + r_a) * K + k0 + kc];
    __syncthreads();
    *(uint4*)&As[(     r_a) * 32 + kc] = av0;
    *(uint4*)&As[(64 + r_a) * 32 + kc] = av1;
    *(uint4*)&Bs[(     r_a) * 32 + kc] = bv0;
    *(uint4*)&Bs[(64 + r_a) * 32 + kc] = bv1;
    __syncthreads();
    bf16x8 af[4], bfv[4];
    #pragma unroll
    for (int i = 0; i < 4; ++i) af[i]  = *(const bf16x8*)&As[(wr + i*16 + m_l)*32 + quad*8];
    #pragma unroll
    for (int j = 0; j < 4; ++j) bfv[j] = *(const bf16x8*)&Bs[(wc + j*16 + m_l)*32 + quad*8];
    #pragma unroll
    for (int i = 0; i < 4; ++i)
      #pragma unroll
      for (int j = 0; j < 4; ++j)
        acc[i][j] = __builtin_amdgcn_mfma_f32_16x16x32_bf16(af[i], bfv[j], acc[i][j], 0, 0, 0);
  }
  float* P = (blockIdx.z == 0) ? P0 : (blockIdx.z == 1) ? P1 : (blockIdx.z == 2) ? P2 : P3;
  #pragma unroll
  for (int i = 0; i < 4; ++i) {
    #pragma unroll
    for (int j = 0; j < 4; ++j) {
      int col = col0 + wc + j*16 + m_l;
      if (col < N) {
        #pragma unroll
        for (int r = 0; r < 4; ++r) {
          int row = row0 + wr + i*16 + quad*4 + r;
          P[(size_t)row*N + col] = acc[i][j][r];
        }
      }
    }
  }
}

// ---------------- split-K reduce: dst (+)= epi(sum of Z partials) ------------
template<int Z, int EPI, bool ADD>
__global__ void k_reduce(float* __restrict__ dst, const float* __restrict__ p0,
                         const float* __restrict__ p1, const float* __restrict__ p2,
                         const float* __restrict__ p3) {
  size_t i = ((size_t)blockIdx.x*256 + threadIdx.x)*4;
  float4 a = *(const float4*)(p0 + i);
  float4 b = *(const float4*)(p1 + i);
  float r0 = a.x + b.x, r1 = a.y + b.y, r2 = a.z + b.z, r3 = a.w + b.w;
  if (Z == 4) {
    float4 c = *(const float4*)(p2 + i);
    float4 d = *(const float4*)(p3 + i);
    r0 += c.x + d.x; r1 += c.y + d.y; r2 += c.z + d.z; r3 += c.w + d.w;
  }
  if (EPI == 2) {
    r0 = 1.f/(1.f + __expf(-r0)); r1 = 1.f/(1.f + __expf(-r1));
    r2 = 1.f/(1.f + __expf(-r2)); r3 = 1.f/(1.f + __expf(-r3));
  }
  if (ADD) {
    float4 o = *(const float4*)(dst + i);
    r0 += o.x; r1 += o.y; r2 += o.z; r3 += o.w;
  }
  float4 res; res.x = r0; res.y = r1; res.z = r2; res.w = r3;
  *(float4*)(dst + i) = res;
}

// ---------------- SSM conv (K=4) + silu + dt softplus; bf16 xBC out ----------
__global__ void k_conv_ssm(const float* __restrict__ ZXr, const float* __restrict__ cw,
                           const float* __restrict__ cb, const float* __restrict__ dtb,
                           bf16* __restrict__ XBCb, float* __restrict__ DT) {
  int bt = blockIdx.x; int b = bt >> 10; int t = bt & 1023;
  int tid = threadIdx.x;
  for (int c = tid; c < NXBC; c += 256) {
    float acc = cb[c];
    #pragma unroll
    for (int kk = 0; kk < 4; ++kk) {
      int ts = t - 3 + kk;
      if (ts >= 0) acc += cw[c*4+kk] * ZXr[((size_t)(b*TT+ts))*NXBCD + c];
    }
    float s = acc / (1.f + __expf(-acc));  // silu
    XBCb[(size_t)bt*NXBC + c] = f2b(s);
  }
  if (tid < NHS) {
    float x = ZXr[(size_t)bt*NXBCD + NXBC + tid] + dtb[tid];
    float sp = (x > 20.f) ? x : log1pf(__expf(x));
    DT[(size_t)bt*NHS + tid] = sp;
  }
}

// ---------------- scan pass 1: intra-chunk via MFMA (Mamba2 chunked) ---------
__global__ __launch_bounds__(256)
void k_scan1(const bf16* __restrict__ xbcb, const float* __restrict__ dt,
             const float* __restrict__ A_log, const float* __restrict__ Dmv,
             float* __restrict__ Y, float* __restrict__ SC, float* __restrict__ CUM) {
  int bc = blockIdx.x;
  int bh = bc >> 3, c = bc & 7;
  int b = bh >> 5, h = bh & 31;
  int tid = threadIdx.x, wave = tid >> 6, lane = tid & 63;
  int col = lane & 15, quad = lane >> 4;
  int t0 = c * CL;
  __shared__ bf16 sB[128*136];   // B rows [s][n]; later BwT [n][s]
  __shared__ bf16 sC[128*136];   // C rows [t][n]; later Ps [t][s]
  __shared__ bf16 sxT[64*136];   // x^T [p][t]
  __shared__ float sL[128], sdt[128];
  float A = -__expf(A_log[h]);
  float Dmh = Dmv[h];
  for (int e = tid; e < 128*16; e += 256) {
    int r = e >> 4, ch = e & 15;
    const bf16* row = xbcb + (size_t)(b*TT + t0 + r)*NXBC;
    *(uint4*)&sB[r*136 + ch*8] = *(const uint4*)&row[2048 + ch*8];
    *(uint4*)&sC[r*136 + ch*8] = *(const uint4*)&row[2176 + ch*8];
  }
  for (int e = tid; e < 64*128; e += 256) {
    int p = e & 63, t = e >> 6;
    sxT[p*136 + t] = xbcb[(size_t)(b*TT + t0 + t)*NXBC + h*64 + p];
  }
  if (tid < 128) sdt[tid] = dt[(size_t)(b*TT + t0 + tid)*NHS + h];
  __syncthreads();
  if (wave == 0) {
    float a0 = sdt[2*lane]*A, a1 = sdt[2*lane+1]*A;
    float tot = a0 + a1;
    #pragma unroll
    for (int off = 1; off < 64; off <<= 1) {
      float up = __shfl_up(tot, off);
      if (lane >= off) tot += up;
    }
    sL[2*lane+1] = tot;
    sL[2*lane]   = tot - a1;
  }
  __syncthreads();
  int wr = (wave & 1)*64, wc = (wave >> 1)*64;
  f32x4 g[4][4];
  #pragma unroll
  for (int i = 0; i < 4; ++i)
    #pragma unroll
    for (int j = 0; j < 4; ++j) g[i][j] = (f32x4){0.f,0.f,0.f,0.f};
  #pragma unroll
  for (int kf = 0; kf < 4; ++kf) {
    bf16x8 af[4], bfr[4];
    #pragma unroll
    for (int i = 0; i < 4; ++i) af[i]  = *(const bf16x8*)&sC[(wr + i*16 + col)*136 + kf*32 + quad*8];
    #pragma unroll
    for (int j = 0; j < 4; ++j) bfr[j] = *(const bf16x8*)&sB[(wc + j*16 + col)*136 + kf*32 + quad*8];
    #pragma unroll
    for (int i = 0; i < 4; ++i)
      #pragma unroll
      for (int j = 0; j < 4; ++j)
        g[i][j] = __builtin_amdgcn_mfma_f32_16x16x32_bf16(af[i], bfr[j], g[i][j], 0, 0, 0);
  }
  __syncthreads();
  if (tid < 128) CUM[(size_t)bh*TT + t0 + tid] = __expf(sL[tid]);
  float Lend = sL[127];
  #pragma unroll
  for (int i = 0; i < 4; ++i) {
    #pragma unroll
    for (int j = 0; j < 4; ++j) {
      int sl = wc + j*16 + col;
      #pragma unroll
      for (int r = 0; r < 4; ++r) {
        int tl = wr + i*16 + quad*4 + r;
        float v = (sl <= tl) ? g[i][j][r] * __expf(sL[tl] - sL[sl]) * sdt[sl] : 0.f;
        sC[tl*136 + sl] = f2b(v);
      }
    }
  }
  for (int e = tid; e < 128*128; e += 256) {
    int n = e & 127, s = e >> 7;
    float w = __expf(Lend - sL[s]) * sdt[s];
    sB[n*136 + s] = f2b(b2f(xbcb[(size_t)(b*TT + t0 + s)*NXBC + 2048 + n]) * w);
  }
  __syncthreads();
  f32x4 ya[2][4];
  #pragma unroll
  for (int i2 = 0; i2 < 2; ++i2)
    #pragma unroll
    for (int jd = 0; jd < 4; ++jd) ya[i2][jd] = (f32x4){0.f,0.f,0.f,0.f};
  #pragma unroll
  for (int kf = 0; kf < 4; ++kf) {
    bf16x8 pa[2], xa[4];
    #pragma unroll
    for (int i2 = 0; i2 < 2; ++i2)
      pa[i2] = *(const bf16x8*)&sC[(wave*32 + i2*16 + col)*136 + kf*32 + quad*8];
    #pragma unroll
    for (int jd = 0; jd < 4; ++jd)
      xa[jd] = *(const bf16x8*)&sxT[(jd*16 + col)*136 + kf*32 + quad*8];
    #pragma unroll
    for (int i2 = 0; i2 < 2; ++i2)
      #pragma unroll
      for (int jd = 0; jd < 4; ++jd)
        ya[i2][jd] = __builtin_amdgcn_mfma_f32_16x16x32_bf16(pa[i2], xa[jd], ya[i2][jd], 0, 0, 0);
  }
  #pragma unroll
  for (int i2 = 0; i2 < 2; ++i2) {
    #pragma unroll
    for (int jd = 0; jd < 4; ++jd) {
      int p = jd*16 + col;
      #pragma unroll
      for (int r = 0; r < 4; ++r) {
        int tl = wave*32 + i2*16 + quad*4 + r;
        float xv = b2f(sxT[p*136 + tl]);
        Y[(size_t)(b*TT + t0 + tl)*DI + h*64 + p] = ya[i2][jd][r] + xv*Dmh;
      }
    }
  }
  f32x4 sa[8];
  #pragma unroll
  for (int nt = 0; nt < 8; ++nt) sa[nt] = (f32x4){0.f,0.f,0.f,0.f};
  #pragma unroll
  for (int kf = 0; kf < 4; ++kf) {
    bf16x8 xpa = *(const bf16x8*)&sxT[(wave*16 + col)*136 + kf*32 + quad*8];
    #pragma unroll
    for (int nt = 0; nt < 8; ++nt) {
      bf16x8 bwa = *(const bf16x8*)&sB[(nt*16 + col)*136 + kf*32 + quad*8];
      sa[nt] = __builtin_amdgcn_mfma_f32_16x16x32_bf16(xpa, bwa, sa[nt], 0, 0, 0);
    }
  }
  #pragma unroll
  for (int nt = 0; nt < 8; ++nt) {
    int n = nt*16 + col;
    #pragma unroll
    for (int r = 0; r < 4; ++r) {
      int p = wave*16 + quad*4 + r;
      SC[((size_t)(bh*NC + c)*64 + p)*128 + n] = sa[nt][r];
    }
  }
}

// ---------------- scan pass 2: sequential inter-chunk combine (fp32) ---------
__global__ __launch_bounds__(512)
void k_scan2(float* __restrict__ SC, const float* __restrict__ CUM) {
  int bh = blockIdx.x;
  int tid = threadIdx.x;
  int p = tid >> 3, g = tid & 7;
  float S[16];
  #pragma unroll
  for (int j = 0; j < 16; ++j) S[j] = 0.f;
  for (int c = 0; c < NC; ++c) {
    size_t base = ((size_t)(bh*NC + c)*64 + p)*128 + g*16;
    float Ptot = CUM[(size_t)bh*TT + c*CL + (CL-1)];
    float tmp[16];
    #pragma unroll
    for (int j = 0; j < 16; ++j) tmp[j] = SC[base + j];
    #pragma unroll
    for (int j = 0; j < 16; ++j) SC[base + j] = S[j];
    #pragma unroll
    for (int j = 0; j < 16; ++j) S[j] = S[j]*Ptot + tmp[j];
  }
}

// ---------------- scan pass 3: Y += CUM[t] * (C @ S_init^T) via MFMA ---------
__global__ __launch_bounds__(256)
void k_scan3(const bf16* __restrict__ xbcb, const float* __restrict__ SC,
             const float* __restrict__ CUM, float* __restrict__ Y) {
  int bc = blockIdx.x;
  int bh = bc >> 3, c = bc & 7;
  if (c == 0) return;
  int b = bh >> 5, h = bh & 31;
  int tid = threadIdx.x, wave = tid >> 6, lane = tid & 63;
  int col = lane & 15, quad = lane >> 4;
  int t0 = c * CL;
  __shared__ bf16 sCt[128*136];
  __shared__ bf16 sS[64*136];
  __shared__ float sCum[128];
  for (int e = tid; e < 128*16; e += 256) {
    int r = e >> 4, ch = e & 15;
    *(uint4*)&sCt[r*136 + ch*8] =
      *(const uint4*)&xbcb[(size_t)(b*TT + t0 + r)*NXBC + 2176 + ch*8];
  }
  for (int e = tid; e < 64*128; e += 256) {
    int n = e & 127, p = e >> 7;
    sS[p*136 + n] = f2b(SC[((size_t)(bh*NC + c)*64 + p)*128 + n]);
  }
  if (tid < 128) sCum[tid] = CUM[(size_t)bh*TT + t0 + tid];
  __syncthreads();
  f32x4 ya[2][4];
  #pragma unroll
  for (int i2 = 0; i2 < 2; ++i2)
    #pragma unroll
    for (int jd = 0; jd < 4; ++jd) ya[i2][jd] = (f32x4){0.f,0.f,0.f,0.f};
  #pragma unroll
  for (int kf = 0; kf < 4; ++kf) {
    bf16x8 pa[2], sv[4];
    #pragma unroll
    for (int i2 = 0; i2 < 2; ++i2)
      pa[i2] = *(const bf16x8*)&sCt[(wave*32 + i2*16 + col)*136 + kf*32 + quad*8];
    #pragma unroll
    for (int jd = 0; jd < 4; ++jd)
      sv[jd] = *(const bf16x8*)&sS[(jd*16 + col)*136 + kf*32 + quad*8];
    #pragma unroll
    for (int i2 = 0; i2 < 2; ++i2)
      #pragma unroll
      for (int jd = 0; jd < 4; ++jd)
        ya[i2][jd] = __builtin_amdgcn_mfma_f32_16x16x32_bf16(pa[i2], sv[jd], ya[i2][jd], 0, 0, 0);
  }
  #pragma unroll
  for (int i2 = 0; i2 < 2; ++i2) {
    #pragma unroll
    for (int jd = 0; jd < 4; ++jd) {
      int p = jd*16 + col;
      #pragma unroll
      for (int r = 0; r < 4; ++r) {
        int tl = wave*32 + i2*16 + quad*4 + r;
        Y[(size_t)(b*TT + t0 + tl)*DI + h*64 + p] += sCum[tl]*ya[i2][jd][r];
      }
    }
  }
}

// ---------------- gate: Ybf = bf16(rmsnorm(y * silu(z)) * mnorm_w) -----------
__global__ void k_gate(const float* __restrict__ Y, const float* __restrict__ Z,
                       const float* __restrict__ mnw, bf16* __restrict__ Ybf) {
  int row = blockIdx.x; int tid = threadIdx.x;
  const float* yr = Y + (size_t)row*DI;
  const float* zr = Z + (size_t)row*DI;
  float gv[8]; float ss = 0.f;
  #pragma unroll
  for (int i = 0; i < 8; ++i) {
    int c = tid*8 + i;
    float z = zr[c];
    float sz = z / (1.f + __expf(-z));
    float v = yr[c]*sz;
    gv[i] = v; ss += v*v;
  }
  __shared__ float red[256];
  red[tid] = ss; __syncthreads();
  for (int s = 128; s > 0; s >>= 1) { if (tid < s) red[tid] += red[tid+s]; __syncthreads(); }
  float scale = rsqrtf(red[0]/(float)DI + 1e-5f);
  bf16* br = Ybf + (size_t)row*DI;
  #pragma unroll
  for (int i = 0; i < 8; ++i) { int c = tid*8 + i; br[c] = f2b(gv[i]*scale*mnw[c]); }
}

// ---------------- q/k/v causal dwconv (K=3), bf16 out, Q pre-scaled, V^T -----
__global__ void k_conv_qkv(const float* __restrict__ QKV,
                           const float* qw, const float* qb, const float* kw, const float* kb,
                           const float* vw, const float* vb,
                           bf16* __restrict__ Qb, bf16* __restrict__ Kb, bf16* __restrict__ Vtb) {
  int bt = blockIdx.x; int b = bt >> 10; int t = bt & 1023;
  int tid = threadIdx.x;
  for (int c = tid; c < 1152; c += 256) {
    if (c < 1024) {
      int h = c >> 6, d = c & 63;
      float acc = qb[d];
      #pragma unroll
      for (int kk = 0; kk < 3; ++kk) { int ts = t-2+kk; if (ts >= 0) acc += qw[d*3+kk] * QKV[((size_t)(b*TT+ts))*1152 + c]; }
      Qb[((size_t)(b*NHA + h)*TT + t)*HD + d] = f2b(acc * 0.125f);  // 1/sqrt(64)
    } else if (c < 1088) {
      int d = c - 1024;
      float acc = kb[d];
      #pragma unroll
      for (int kk = 0; kk < 3; ++kk) { int ts = t-2+kk; if (ts >= 0) acc += kw[d*3+kk] * QKV[((size_t)(b*TT+ts))*1152 + c]; }
      Kb[(size_t)bt*HD + d] = f2b(acc);
    } else {
      int d = c - 1088;
      float acc = vb[d];
      #pragma unroll
      for (int kk = 0; kk < 3; ++kk) { int ts = t-2+kk; if (ts >= 0) acc += vw[d*3+kk] * QKV[((size_t)(b*TT+ts))*1152 + c]; }
      Vtb[((size_t)(b*HD + d))*TT + t] = f2b(acc);
    }
  }
}

// ---------------- MFMA flash attention ---------------------------------------
__global__ __launch_bounds__(256)
void k_flash(const bf16* __restrict__ Qb, const bf16* __restrict__ Kb,
             const bf16* __restrict__ Vtb, bf16* __restrict__ out) {
  int qt = blockIdx.x, h = blockIdx.y, b = blockIdx.z;
  int tid = threadIdx.x, wave = tid >> 6, lane = tid & 63;
  int col = lane & 15, quad = lane >> 4;
  int t0 = qt * 128;
  __shared__ bf16 Ks[128*72];
  __shared__ bf16 Vs[64*136];
  __shared__ bf16 Ps[4][32*136];
  const bf16* Qbase = Qb + ((size_t)(b*NHA + h))*TT*HD;
  bf16x8 qf[2][2];
  #pragma unroll
  for (int i = 0; i < 2; ++i)
    #pragma unroll
    for (int kf = 0; kf < 2; ++kf)
      qf[i][kf] = *(const bf16x8*)&Qbase[(size_t)(t0 + wave*32 + i*16 + col)*HD + kf*32 + quad*8];
  float mst[2][4], lst[2][4];
  f32x4 oacc[2][4];
  #pragma unroll
  for (int i = 0; i < 2; ++i)
    #pragma unroll
    for (int r = 0; r < 4; ++r) { mst[i][r] = -1e30f; lst[i][r] = 0.f; }
  #pragma unroll
  for (int i = 0; i < 2; ++i)
    #pragma unroll
    for (int jd = 0; jd < 4; ++jd) oacc[i][jd] = (f32x4){0.f,0.f,0.f,0.f};

  for (int kt = 0; kt <= qt; ++kt) {
    int s0 = kt * 128;
    __syncthreads();
    for (int e = tid; e < 1024; e += 256) {
      int r = e >> 3, ch = e & 7;
      *(uint4*)&Ks[r*72 + ch*8] = *(const uint4*)&Kb[((size_t)(b*TT + s0 + r))*HD + ch*8];
    }
    for (int e = tid; e < 1024; e += 256) {
      int d = e >> 4, ch = e & 15;
      *(uint4*)&Vs[d*136 + ch*8] = *(const uint4*)&Vtb[((size_t)(b*HD + d))*TT + s0 + ch*8];
    }
    __syncthreads();
    f32x4 sacc[2][8];
    #pragma unroll
    for (int i = 0; i < 2; ++i)
      #pragma unroll
      for (int j = 0; j < 8; ++j) sacc[i][j] = (f32x4){0.f,0.f,0.f,0.f};
    #pragma unroll
    for (int j = 0; j < 8; ++j) {
      bf16x8 kf0 = *(const bf16x8*)&Ks[(j*16 + col)*72 + quad*8];
      bf16x8 kf1 = *(const bf16x8*)&Ks[(j*16 + col)*72 + 32 + quad*8];
      #pragma unroll
      for (int i = 0; i < 2; ++i) {
        sacc[i][j] = __builtin_amdgcn_mfma_f32_16x16x32_bf16(qf[i][0], kf0, sacc[i][j], 0, 0, 0);
        sacc[i][j] = __builtin_amdgcn_mfma_f32_16x16x32_bf16(qf[i][1], kf1, sacc[i][j], 0, 0, 0);
      }
    }
    bool diag = (kt == qt);
    #pragma unroll
    for (int i = 0; i < 2; ++i) {
      #pragma unroll
      for (int r = 0; r < 4; ++r) {
        int rowloc = wave*32 + i*16 + quad*4 + r;
        if (diag) {
          #pragma unroll
          for (int j = 0; j < 8; ++j)
            if (j*16 + col > rowloc) sacc[i][j][r] = -1e30f;
        }
        float mx = -1e30f;
        #pragma unroll
        for (int j = 0; j < 8; ++j) mx = fmaxf(mx, sacc[i][j][r]);
        mx = fmaxf(mx, __shfl_xor(mx, 1));
        mx = fmaxf(mx, __shfl_xor(mx, 2));
        mx = fmaxf(mx, __shfl_xor(mx, 4));
        mx = fmaxf(mx, __shfl_xor(mx, 8));
        float nm = fmaxf(mst[i][r], mx);
        float alpha = __expf(mst[i][r] - nm);
        float sum = 0.f;
        #pragma unroll
        for (int j = 0; j < 8; ++j) {
          float pv = __expf(sacc[i][j][r] - nm);
          sacc[i][j][r] = pv; sum += pv;
        }
        sum += __shfl_xor(sum, 1);
        sum += __shfl_xor(sum, 2);
        sum += __shfl_xor(sum, 4);
        sum += __shfl_xor(sum, 8);
        lst[i][r] = lst[i][r]*alpha + sum;
        mst[i][r] = nm;
        #pragma unroll
        for (int jd = 0; jd < 4; ++jd) oacc[i][jd][r] *= alpha;
      }
    }
    #pragma unroll
    for (int i = 0; i < 2; ++i)
      #pragma unroll
      for (int j = 0; j < 8; ++j)
        #pragma unroll
        for (int r = 0; r < 4; ++r)
          Ps[wave][(i*16 + quad*4 + r)*136 + j*16 + col] = f2b(sacc[i][j][r]);
    #pragma unroll
    for (int i = 0; i < 2; ++i) {
      bf16x8 pa[4];
      #pragma unroll
      for (int kf = 0; kf < 4; ++kf)
        pa[kf] = *(const bf16x8*)&Ps[wave][(i*16 + col)*136 + kf*32 + quad*8];
      #pragma unroll
      for (int jd = 0; jd < 4; ++jd) {
        #pragma unroll
        for (int kf = 0; kf < 4; ++kf) {
          bf16x8 vbf = *(const bf16x8*)&Vs[(jd*16 + col)*136 + kf*32 + quad*8];
          oacc[i][jd] = __builtin_amdgcn_mfma_f32_16x16x32_bf16(pa[kf], vbf, oacc[i][jd], 0, 0, 0);
        }
      }
    }
  }
  #pragma unroll
  for (int i = 0; i < 2; ++i) {
    #pragma unroll
    for (int jd = 0; jd < 4; ++jd) {
      int d = jd*16 + col;
      #pragma unroll
      for (int r = 0; r < 4; ++r) {
        int t = t0 + wave*32 + i*16 + quad*4 + r;
        out[((size_t)(b*TT + t))*DM + h*64 + d] = f2b(oacc[i][jd][r] / lst[i][r]);
      }
    }
  }
}

// ---------------- token shift (bf16 in/out) ----------------------------------
__global__ void k_tshift(const bf16* __restrict__ H, const float* __restrict__ maak,
                         const float* __restrict__ maar,
                         bf16* __restrict__ XK, bf16* __restrict__ XR) {
  int idx = blockIdx.x*256 + threadIdx.x;
  int c = idx & (DM - 1);
  int bt = idx >> 10;
  int t = bt & (TT - 1);
  float h = b2f(H[idx]);
  float prev = (t > 0) ? b2f(H[idx - DM]) : 0.f;
  float xx = prev - h;
  XK[idx] = f2b(h + xx*maak[c]);
  XR[idx] = f2b(h + xx*maar[c]);
}

// ---------------- final: out = x + sigmoid_r * kv ----------------------------
__global__ void k_final(const float* __restrict__ X, const float* __restrict__ R,
                        const float* __restrict__ KV, float* __restrict__ out) {
  int idx = blockIdx.x*256 + threadIdx.x;
  out[idx] = X[idx] + R[idx]*KV[idx];
}

// =============================================================================
extern "C" void kernel_launch(void* const* d_in, const int* in_sizes, int n_in,
                              void* d_out, int out_size, void* d_ws, size_t ws_size,
                              hipStream_t stream) {
  const float* x_in    = (const float*)d_in[0];
  const float* W_in    = (const float*)d_in[1];
  const float* conv_w  = (const float*)d_in[2];
  const float* conv_b  = (const float*)d_in[3];
  const float* A_log   = (const float*)d_in[4];
  const float* Dm      = (const float*)d_in[5];
  const float* dt_bias = (const float*)d_in[6];
  const float* mnorm_w = (const float*)d_in[7];
  const float* W_out   = (const float*)d_in[8];
  const float* W_qkv   = (const float*)d_in[9];
  const float* W_cproj = (const float*)d_in[10];
  const float* qconv_w = (const float*)d_in[11];
  const float* qconv_b = (const float*)d_in[12];
  const float* kconv_w = (const float*)d_in[13];
  const float* kconv_b = (const float*)d_in[14];
  const float* vconv_w = (const float*)d_in[15];
  const float* vconv_b = (const float*)d_in[16];
  const float* maa_k   = (const float*)d_in[17];
  const float* maa_r   = (const float*)d_in[18];
  const float* W_key   = (const float*)d_in[19];
  const float* W_rec   = (const float*)d_in[20];
  const float* W_val   = (const float*)d_in[21];
  float* out = (float*)d_out;

  float* ws = (float*)d_ws;
  float* X       = ws;                       // [0, 2,097,152)
  bf16*  Hbf     = (bf16*)(ws + 2097152);    // 2,097,152 bf16
  float* Zbuf    = ws + 3145728;             // [3,145,728, 7,340,032)
  float* XBCDraw = ws + 7340032;             // [7,340,032, 12,124,160)
  float* XBC     = ws + 12124160;            // [12,124,160, 16,842,752)
  float* DT      = ws + 16842752;            // +65,536
  float* CUM     = ws + 16908288;            // +65,536
  float* Y       = ws + 16973824;            // [16,973,824, 21,168,128)

  bf16*  Wt_in    = (bf16*)XBC;
  bf16*  XBCb     = (bf16*)XBC;
  float* SC       = XBCDraw;
  bf16*  Ybf      = (bf16*)XBC;
  bf16*  Wt_out   = (bf16*)(XBC + 2097152);
  float* QKV      = Zbuf;
  bf16*  Wt_qkv   = (bf16*)XBC;
  bf16*  Qb       = (bf16*)XBCDraw;
  bf16*  Kb       = (bf16*)(XBCDraw + 1048576);
  bf16*  Vtb      = (bf16*)(XBCDraw + 1114112);
  bf16*  ATTNbf   = (bf16*)Y;
  bf16*  Wt_cproj = (bf16*)(Y + 1048576);
  bf16*  XKbf     = (bf16*)XBC;
  bf16*  XRbf     = (bf16*)(XBC + 1048576);
  bf16*  Wt_key   = (bf16*)Zbuf;
  bf16*  KFbf     = (bf16*)XBCDraw;
  bf16*  Wt_val   = (bf16*)Zbuf;
  float* KV       = Y;
  float* R        = Y + 2097152;
  bf16*  Wt_rec   = (bf16*)Zbuf;

  dim3 thr256(256), thr512(512);
  dim3 tblk(32, 8);

  // 1. X = x; Hbf = rmsnorm(x)
  k_rms_in<<<BT, thr256, 0, stream>>>(x_in, X, Hbf);
  // 2. [Z | XBCDraw] = Hbf @ W_in  (wide, full-K)
  k_tcast<<<dim3(4480/32, 1024/32), tblk, 0, stream>>>(W_in, Wt_in, 1024, NZX);
  mfma_gemm<0,false,false><<<dim3(16, 16), thr256, 0, stream>>>(Hbf, Wt_in, Zbuf, nullptr, BT, 2048, 1024);
  mfma_gemm<0,false,false><<<dim3(19, 16), thr256, 0, stream>>>(Hbf, Wt_in + (size_t)2048*1024, XBCDraw, nullptr, BT, NXBCD, 1024);
  // 3. conv+silu on xBC (bf16 out), softplus dt
  k_conv_ssm<<<BT, thr256, 0, stream>>>(XBCDraw, conv_w, conv_b, dt_bias, XBCb, DT);
  // 4. SSM chunked scan via MFMA
  k_scan1<<<BB*NHS*NC, thr256, 0, stream>>>(XBCb, DT, A_log, Dm, Y, SC, CUM);
  k_scan2<<<BB*NHS, thr512, 0, stream>>>(SC, CUM);
  k_scan3<<<BB*NHS*NC, thr256, 0, stream>>>(XBCb, SC, CUM, Y);
  // 5. gate + mnorm -> Ybf
  k_gate<<<BT, thr256, 0, stream>>>(Y, Zbuf, mnorm_w, Ybf);
  // 6. X += Ybf @ W_out  (split-K z=4 -> 512 blocks, BK=32 kernel)
  k_tcast<<<dim3(1024/32, 2048/32), tblk, 0, stream>>>(W_out, Wt_out, 2048, 1024);
  mfma_sk32<<<dim3(8, 16, 4), thr256, 0, stream>>>(Ybf, Wt_out,
      Zbuf, Zbuf + 2097152, XBCDraw, XBCDraw + 2097152, BT, 1024, 2048, 512);
  k_reduce<4,0,true><<<2048, thr256, 0, stream>>>(X, Zbuf, Zbuf + 2097152, XBCDraw, XBCDraw + 2097152);
  // 7. Hbf = rmsnorm(X)
  k_rms_f32<<<BT, thr256, 0, stream>>>(X, Hbf);
  // 8. QKV = Hbf @ W_qkv  (split-K z=2 -> 288 blocks)
  k_tcast<<<dim3(1152/32, 1024/32), tblk, 0, stream>>>(W_qkv, Wt_qkv, 1024, 1152);
  mfma_sk32<<<dim3(9, 16, 2), thr256, 0, stream>>>(Hbf, Wt_qkv,
      XBCDraw, XBCDraw + 2359296, XBCDraw, XBCDraw, BT, 1152, 1024, 512);
  k_reduce<2,0,false><<<2304, thr256, 0, stream>>>(QKV, XBCDraw, XBCDraw + 2359296, XBCDraw, XBCDraw);
  // 9. q/k/v convs -> bf16 Qb (scaled), Kb, Vtb (transposed)
  k_conv_qkv<<<BT, thr256, 0, stream>>>(QKV, qconv_w, qconv_b, kconv_w, kconv_b, vconv_w, vconv_b, Qb, Kb, Vtb);
  // 10. MFMA flash attention -> ATTNbf
  k_flash<<<dim3(TT/128, NHA, BB), thr256, 0, stream>>>(Qb, Kb, Vtb, ATTNbf);
  // 11. X += ATTNbf @ W_cproj  (split-K z=2 -> 256 blocks)
  k_tcast<<<dim3(1024/32, 1024/32), tblk, 0, stream>>>(W_cproj, Wt_cproj, 1024, 1024);
  mfma_sk32<<<dim3(8, 16, 2), thr256, 0, stream>>>(ATTNbf, Wt_cproj,
      XBC, XBC + 2097152, XBC, XBC, BT, 1024, 1024, 512);
  k_reduce<2,0,true><<<2048, thr256, 0, stream>>>(X, XBC, XBC + 2097152, XBC, XBC);
  // 12. Hbf = rmsnorm(X)
  k_rms_f32<<<BT, thr256, 0, stream>>>(X, Hbf);
  // 13. token shift -> XKbf, XRbf
  k_tshift<<<(BT*DM)/256, thr256, 0, stream>>>(Hbf, maa_k, maa_r, XKbf, XRbf);
  // 14. KFbf = bf16(relu(XKbf @ W_key)^2)  (wide, full-K, 512 blocks)
  k_tcast<<<dim3(4096/32, 1024/32), tblk, 0, stream>>>(W_key, Wt_key, 1024, 4096);
  mfma_gemm<1,false,true><<<dim3(32, 16), thr256, 0, stream>>>(XKbf, Wt_key, nullptr, KFbf, BT, 4096, 1024);
  // 15. KV = KFbf @ W_val  (split-K z=4 -> 512 blocks)
  k_tcast<<<dim3(1024/32, 4096/32), tblk, 0, stream>>>(W_val, Wt_val, 4096, 1024);
  mfma_sk32<<<dim3(8, 16, 4), thr256, 0, stream>>>(KFbf, Wt_val,
      Y, Y + 2097152, XBC + 2621440, Zbuf + 2097152, BT, 1024, 4096, 1024);
  k_reduce<4,0,false><<<2048, thr256, 0, stream>>>(KV, Y, Y + 2097152, XBC + 2621440, Zbuf + 2097152);
  // 16. R = sigmoid(XRbf @ W_rec)  (split-K z=2 -> 256 blocks)
  k_tcast<<<dim3(1024/32, 1024/32), tblk, 0, stream>>>(W_rec, Wt_rec, 1024, 1024);
  mfma_sk32<<<dim3(8, 16, 2), thr256, 0, stream>>>(XRbf, Wt_rec,
      Y + 2097152, XBC + 2621440, Y, Y, BT, 1024, 1024, 512);
  k_reduce<2,2,false><<<2048, thr256, 0, stream>>>(R, Y + 2097152, XBC + 2621440, Y, Y);
  // 17. out = x + sigmoid_r * kv
  k_final<<<(BT*DM)/256, thr256, 0, stream>>>(X, R, KV, out);
}